// Round 6
// baseline (208.580 us; speedup 1.0000x reference)
//
#include <hip/hip_runtime.h>
#include <hip/hip_bf16.h>

#define DIMC 384          // C
#define LL 785            // 1 + 28*28
#define FDIM 1536         // 4*C  (GEMM K)
#define ODIM 768          // 2*C  (GEMM N)
#define NPATCH 196        // 14*14
#define MROWS 12544       // B*196 (GEMM M)
#define BATCH 64

typedef __attribute__((ext_vector_type(8))) short bf16x8;
typedef __attribute__((ext_vector_type(4))) float floatx4;
typedef __attribute__((ext_vector_type(4))) unsigned short ushort4v;

// ws layout (bytes):
//   wbf   u16[768*1536]   @ 0        (2,359,296 B)  bf16(gamma * w_red)
//   bias2 f32x2[768]      @ 2359296  (    6,144 B)  (gsum, bias) per o
#define WS_B2_OFF 2359296

// prep role bases
#define PB_CLS   0       // 192 cls blocks
#define PB_BIAS  192     // 192 bias2 blocks
#define PB_WBF   384     // 1152 wbf blocks
#define PREP_BLOCKS 1536

__device__ __forceinline__ unsigned short f2bf(float f) {
  union { float f; unsigned int u; } v; v.f = f;
  unsigned int u = v.u + 0x7fffu + ((v.u >> 16) & 1u);   // RNE
  return (unsigned short)(u >> 16);
}

__device__ __forceinline__ void gload_lds16(const void* g, void* l) {
  __builtin_amdgcn_global_load_lds(
      (const __attribute__((address_space(1))) unsigned int*)g,
      (__attribute__((address_space(3))) unsigned int*)l, 16, 0, 0);
}

// ---------------------------------------------------------------------------
// Prep kernel (small): weights-only + cls. The x cast/stats moved INTO the
// GEMM (fused), deleting the 38.5 MB xbf write + 38.5 MB re-read.
//  bias2: (gsum[o], bias[o]) = (sum_f gamma*wred, sum_f beta*wred)
//  wbf:   bf16(gamma * w_red);  cls: out[b,0,:] = wconv @ x[b,0,:]
// ---------------------------------------------------------------------------
__global__ __launch_bounds__(256) void prep_kernel(
    const float* __restrict__ x, const float* __restrict__ wred,
    const float* __restrict__ wconv, const float* __restrict__ gamma,
    const float* __restrict__ beta, unsigned short* __restrict__ wbf,
    float2* __restrict__ bias2, float* __restrict__ out) {
  const int blk = blockIdx.x;
  const int t = threadIdx.x;
  const int wv = t >> 6;
  const int lane = t & 63;

  if (blk < PB_BIAS) {                     // ---- cls ----
    __shared__ float xs[DIMC];
    int idx = blk;                         // < 192
    int b = idx / 3;
    int ch = idx - b * 3;
    for (int c = t; c < DIMC; c += 256) xs[c] = x[(size_t)b * LL * DIMC + c];
    __syncthreads();
    int o = ch * 256 + t;
    const float* wr = wconv + (size_t)o * DIMC;
    float a0 = 0.f, a1 = 0.f;
#pragma unroll 4
    for (int c = 0; c < DIMC; c += 8) {
      float4 w0 = *reinterpret_cast<const float4*>(wr + c);
      float4 w1 = *reinterpret_cast<const float4*>(wr + c + 4);
      float4 p0 = *reinterpret_cast<const float4*>(&xs[c]);
      float4 p1 = *reinterpret_cast<const float4*>(&xs[c + 4]);
      a0 += w0.x * p0.x + w0.y * p0.y + w0.z * p0.z + w0.w * p0.w;
      a1 += w1.x * p1.x + w1.y * p1.y + w1.z * p1.z + w1.w * p1.w;
    }
    out[(size_t)b * 197 * ODIM + o] = a0 + a1;
  } else if (blk < PB_WBF) {               // ---- bias2 = (gsum, bias) ----
    int o = (blk - PB_BIAS) * 4 + wv;      // < 768
    const float* wr = wred + (size_t)o * FDIM;
    float sb = 0.f, sg = 0.f;
#pragma unroll
    for (int c = 0; c < 6; ++c) {
      int f = lane * 4 + c * 256;
      float4 w = *reinterpret_cast<const float4*>(wr + f);
      float4 be = *reinterpret_cast<const float4*>(beta + f);
      float4 ga = *reinterpret_cast<const float4*>(gamma + f);
      sb += w.x * be.x + w.y * be.y + w.z * be.z + w.w * be.w;
      sg += w.x * ga.x + w.y * ga.y + w.z * ga.z + w.w * ga.w;
    }
#pragma unroll
    for (int o2 = 32; o2 > 0; o2 >>= 1) {
      sb += __shfl_down(sb, o2);
      sg += __shfl_down(sg, o2);
    }
    if (lane == 0) bias2[o] = make_float2(sg, sb);
  } else {                                 // ---- wbf = bf16(gamma*w_red) ----
    int idx4 = (blk - PB_WBF) * 256 + t;   // < 294912
    int e0 = idx4 * 4;
    int f = e0 % FDIM;
    float4 w = *reinterpret_cast<const float4*>(wred + e0);
    float4 g = *reinterpret_cast<const float4*>(gamma + f);
    ushort4v u;
    u.x = f2bf(w.x * g.x); u.y = f2bf(w.y * g.y);
    u.z = f2bf(w.z * g.z); u.w = f2bf(w.w * g.w);
    *reinterpret_cast<ushort4v*>(wbf + e0) = u;
  }
}

// ---------------------------------------------------------------------------
// FUSED GEMM: reads x (f32) directly. Tile 128x128, BK=64, 256 thr, proven
// 2-barrier schedule. A path is reg-staged (T14 issue-early/write-late):
//   (a) barrier: prev readers done + next A f32 regs arrived (vmcnt drain)
//   staging: cvt A regs->bf16 ds_write (swizzled) + stats fma; B gload_lds
//   (b) barrier: LDS ready (drains ds_write + B only)
//   issue A f32 loads for tile kt+1  <-- overlap the whole MFMA phase
//   ds_read frags + MFMA
// Row stats (s,s2) accumulate in-pass (each thread owns 4 rows x 1 chunk);
// 3-level shfl among the 8 same-row lanes after the K-loop -> st[] -> affine
// LN epilogue: C = rs[m]*acc + nmu[m]*gsum[o] + bias[o].
// ---------------------------------------------------------------------------
__global__ __launch_bounds__(256) void gemm_kernel(
    const float* __restrict__ x,
    const unsigned short* __restrict__ wbf,
    const float2* __restrict__ bias2, float* __restrict__ out) {
  __shared__ unsigned short As[128 * 64];   // 16 KB
  __shared__ unsigned short Bs[128 * 64];   // 16 KB
  __shared__ float2 st[128];                // per-row (rs, nmu)

  const int t = threadIdx.x;

  // ---- chunked bijective XCD swizzle: NWG=588, q=73, r=4 ----
  const int NWG = (ODIM / 128) * (MROWS / 128);   // 588
  const int qq = NWG >> 3, rr = NWG & 7;
  int bid = blockIdx.x;
  int xcd = bid & 7, pos = bid >> 3;
  int wg = (xcd < rr) ? xcd * (qq + 1) + pos
                      : rr * (qq + 1) + (xcd - rr) * qq + pos;
  int my = wg / 6;                        // consecutive wg share my (A-panel)
  int nx = wg - my * 6;
  const int mBase = my * 128;
  const int nBase = nx * 128;

  // Staging precompute: slot s = p*256+t -> row r=s>>3, chunk c0=s&7;
  // source chunk cs = c0 ^ (r&7) (XOR swizzle); LDS dest = s*16 bytes.
  // A source: x row (b, 1 + (2i + q&1)*28 + (2j + (q>>1)&1)), f32.
  const float* agp[4];
  const unsigned short* bgp[4];
  unsigned int ldso[4];
#pragma unroll
  for (int p = 0; p < 4; ++p) {
    int s = p * 256 + t;
    int r = s >> 3;
    int cs = (s & 7) ^ (r & 7);
    int m = mBase + r;
    int b = m / NPATCH;
    int n = m - b * NPATCH;
    int i = n / 14;
    int j = n - i * 14;
    agp[p] = x + ((size_t)b * LL + 1 + i * 56 + j * 2) * DIMC + cs * 8;
    bgp[p] = wbf + (size_t)(nBase + r) * FDIM + cs * 8;
    ldso[p] = (unsigned)s * 8;
  }

  const int wv = t >> 6;
  const int lane = t & 63;
  const int ln15 = lane & 15;
  const int quad = lane >> 4;
  const int wm = wv >> 1;
  const int wn = wv & 1;

  unsigned int aoff[4][2], boff[4][2];
#pragma unroll
  for (int mt = 0; mt < 4; ++mt) {
#pragma unroll
    for (int h = 0; h < 2; ++h) {
      int rA = wm * 64 + mt * 16 + ln15;
      aoff[mt][h] = (unsigned)(rA * 64 + (((h * 4 + quad) ^ (rA & 7)) * 8));
      int rB = wn * 64 + mt * 16 + ln15;
      boff[mt][h] = (unsigned)(rB * 64 + (((h * 4 + quad) ^ (rB & 7)) * 8));
    }
  }

  floatx4 acc[4][4];
#pragma unroll
  for (int mt = 0; mt < 4; ++mt)
#pragma unroll
    for (int nt = 0; nt < 4; ++nt)
      acc[mt][nt] = floatx4{0.f, 0.f, 0.f, 0.f};

  float4 av0[4], av1[4];                   // in-flight A f32 (tile kt)
  float sr[4], s2r[4];
#pragma unroll
  for (int p = 0; p < 4; ++p) { sr[p] = 0.f; s2r[p] = 0.f; }

  // prologue: issue A f32 loads for tile 0 (q=0, kk=0 -> ao=0)
#pragma unroll
  for (int p = 0; p < 4; ++p) {
    av0[p] = *reinterpret_cast<const float4*>(agp[p]);
    av1[p] = *reinterpret_cast<const float4*>(agp[p] + 4);
  }

  for (int kt = 0; kt < FDIM / 64; ++kt) {
    if (kt) __syncthreads();             // (a) readers done; A regs arrived
    // ---- staging: cvt + stats + ds_write A; gload_lds B ----
#pragma unroll
    for (int p = 0; p < 4; ++p) {
      float4 v0 = av0[p], v1 = av1[p];
      sr[p]  += v0.x + v0.y + v0.z + v0.w + v1.x + v1.y + v1.z + v1.w;
      s2r[p] += v0.x * v0.x + v0.y * v0.y + v0.z * v0.z + v0.w * v0.w
              + v1.x * v1.x + v1.y * v1.y + v1.z * v1.z + v1.w * v1.w;
      union { bf16x8 b8; __hip_bfloat162 h[4]; } u;
      u.h[0] = __float22bfloat162_rn(make_float2(v0.x, v0.y));
      u.h[1] = __float22bfloat162_rn(make_float2(v0.z, v0.w));
      u.h[2] = __float22bfloat162_rn(make_float2(v1.x, v1.y));
      u.h[3] = __float22bfloat162_rn(make_float2(v1.z, v1.w));
      *reinterpret_cast<bf16x8*>(&As[ldso[p]]) = u.b8;   // ds_write_b128
    }
#pragma unroll
    for (int p = 0; p < 4; ++p) {
      gload_lds16(bgp[p], &Bs[ldso[p]]);
      bgp[p] += 64;
    }
    __syncthreads();                     // (b) LDS ready (ds_write + B only)

    if (kt + 1 < FDIM / 64) {            // issue NEXT tile's A f32 loads;
      int ktn = kt + 1;                  // they drain at the next (a)
      int q = ktn / 6;
      int kk = ktn - q * 6;
      int ao = ((q & 1) * 28 + ((q >> 1) & 1)) * DIMC + kk * 64;
#pragma unroll
      for (int p = 0; p < 4; ++p) {
        av0[p] = *reinterpret_cast<const float4*>(agp[p] + ao);
        av1[p] = *reinterpret_cast<const float4*>(agp[p] + ao + 4);
      }
    }

    // ---- compute tile kt ----
#pragma unroll
    for (int h = 0; h < 2; ++h) {
      bf16x8 af[4], bfr[4];
#pragma unroll
      for (int mt = 0; mt < 4; ++mt)
        af[mt] = *reinterpret_cast<const bf16x8*>(&As[aoff[mt][h]]);
#pragma unroll
      for (int nt = 0; nt < 4; ++nt)
        bfr[nt] = *reinterpret_cast<const bf16x8*>(&Bs[boff[nt][h]]);
#pragma unroll
      for (int mt = 0; mt < 4; ++mt)
#pragma unroll
        for (int nt = 0; nt < 4; ++nt)
          acc[mt][nt] = __builtin_amdgcn_mfma_f32_16x16x32_bf16(
              af[mt], bfr[nt], acc[mt][nt], 0, 0, 0);
    }
  }

  // ---- row stats: reduce 8 same-row lanes, leaders fill st[] ----
#pragma unroll
  for (int p = 0; p < 4; ++p) {
#pragma unroll
    for (int o = 1; o < 8; o <<= 1) {
      sr[p]  += __shfl_xor(sr[p], o);
      s2r[p] += __shfl_xor(s2r[p], o);
    }
  }
  if ((t & 7) == 0) {
#pragma unroll
    for (int p = 0; p < 4; ++p) {
      float mu = sr[p] * (1.f / FDIM);
      float var = s2r[p] * (1.f / FDIM) - mu * mu;
      float rs = rsqrtf(var + 1e-5f);
      st[p * 32 + (t >> 3)] = make_float2(rs, -mu * rs);
    }
  }
  __syncthreads();

  // Epilogue. C/D: col = ln15, row = quad*4 + reg  [m89/m91].
  // C = rs*acc + nmu*gsum + bias.
  float2 gb[4];
#pragma unroll
  for (int nt = 0; nt < 4; ++nt)
    gb[nt] = bias2[nBase + wn * 64 + nt * 16 + ln15];
#pragma unroll
  for (int mt = 0; mt < 4; ++mt) {
#pragma unroll
    for (int r = 0; r < 4; ++r) {
      int rloc = wm * 64 + mt * 16 + quad * 4 + r;
      float2 sn = st[rloc];              // (rs, nmu)
      int m = mBase + rloc;
      int b = m / NPATCH;
      int n = m - b * NPATCH;
      float* orow = out + ((size_t)b * 197 + 1 + n) * ODIM + nBase + wn * 64;
#pragma unroll
      for (int nt = 0; nt < 4; ++nt) {
        float val = fmaf(acc[mt][nt][r], sn.x,
                         fmaf(sn.y, gb[nt].x, gb[nt].y));
        __builtin_nontemporal_store(val, &orow[nt * 16 + ln15]);
      }
    }
  }
}

extern "C" void kernel_launch(void* const* d_in, const int* in_sizes, int n_in,
                              void* d_out, int out_size, void* d_ws, size_t ws_size,
                              hipStream_t stream) {
  const float* x     = (const float*)d_in[0];   // (64, 785, 384)
  const float* wred  = (const float*)d_in[1];   // (768, 1536)
  const float* wconv = (const float*)d_in[2];   // (768, 384)
  const float* gamma = (const float*)d_in[3];   // (1536,)
  const float* beta  = (const float*)d_in[4];   // (1536,)
  float* out = (float*)d_out;                   // (64, 197, 768)

  unsigned short* wbf = (unsigned short*)d_ws;
  float2* bias2       = (float2*)((char*)d_ws + WS_B2_OFF);

  prep_kernel<<<dim3(PREP_BLOCKS), 256, 0, stream>>>(x, wred, wconv, gamma,
                                                     beta, wbf, bias2, out);
  gemm_kernel<<<dim3((ODIM / 128) * (MROWS / 128)), 256, 0, stream>>>(
      x, wbf, bias2, out);
}

// Round 7
// 196.634 us; speedup vs baseline: 1.0608x; 1.0608x over previous
//
#include <hip/hip_runtime.h>
#include <hip/hip_bf16.h>

#define DIMC 384          // C
#define LL 785            // 1 + 28*28
#define FDIM 1536         // 4*C  (GEMM K)
#define ODIM 768          // 2*C  (GEMM N)
#define NPATCH 196        // 14*14
#define MROWS 12544       // B*196 (GEMM M)
#define BATCH 64

typedef __attribute__((ext_vector_type(8))) short bf16x8;
typedef __attribute__((ext_vector_type(4))) float floatx4;
typedef __attribute__((ext_vector_type(4))) unsigned short ushort4v;

// ws layout (bytes):
//   xbf   u16[50176*384]  @ 0           (38,535,168 B)  bf16(raw x feature rows)
//   wbf   u16[768*1536]   @ 38535168    ( 2,359,296 B)  bf16(gamma * w_red)
//   pst   f32x2[50176]    @ 40894464    (   401,408 B)  per-(b,l) partial (s,s2)
//   bias2 f32x2[768]      @ 41295872    (     6,144 B)  (gsum, bias) per o
#define WS_WBF_OFF  38535168
#define WS_PST_OFF  40894464
#define WS_B2_OFF   41295872

// prep role bases (cls first: latency-bound blocks hide under cast stream)
#define PB_CLS   0
#define PB_CAST  192     // 1568 cast blocks (32 vectors each)
#define PB_BIAS  1760    // 192 bias blocks
#define PB_WBF   1952    // 1152 wbf blocks
#define PREP_BLOCKS 3104

__device__ __forceinline__ unsigned short f2bf(float f) {
  union { float f; unsigned int u; } v; v.f = f;
  unsigned int u = v.u + 0x7fffu + ((v.u >> 16) & 1u);   // RNE
  return (unsigned short)(u >> 16);
}

__device__ __forceinline__ void gload_lds16(const void* g, void* l) {
  __builtin_amdgcn_global_load_lds(
      (const __attribute__((address_space(1))) unsigned int*)g,
      (__attribute__((address_space(3))) unsigned int*)l, 16, 0, 0);
}

// ---------------------------------------------------------------------------
// Prep kernel (R4 verbatim — measured ~36 us).
//  cast+pstat: TWO (b,l) 384-float vectors per quarter-wave; all 12 float4
//    loads issued before any store. Streaming x->bf16 cast + per-vector
//    (s,s2) via 4-level 16-lane shfl off the store path. LayerNorm applied
//    in the GEMM epilogue (affine trick).
//  bias2: (gsum[o], bias[o]);  wbf: bf16(gamma*w_red);  cls: wconv @ x[b,0].
// ---------------------------------------------------------------------------
__global__ __launch_bounds__(256) void prep_kernel(
    const float* __restrict__ x, const float* __restrict__ wred,
    const float* __restrict__ wconv, const float* __restrict__ gamma,
    const float* __restrict__ beta, unsigned short* __restrict__ xbf,
    unsigned short* __restrict__ wbf, float2* __restrict__ pst,
    float2* __restrict__ bias2, float* __restrict__ out) {
  const int blk = blockIdx.x;
  const int t = threadIdx.x;
  const int wv = t >> 6;
  const int lane = t & 63;

  if (blk >= PB_CAST && blk < PB_BIAS) {  // ---- cast + partial stats ----
    const int w = (blk - PB_CAST) * 4 + wv;     // 0..6271
    const int vid0 = w * 8 + (lane >> 4) * 2;   // even; pair stays in one b
    const int sub = lane & 15;
    float4 v[2][6];
    float s[2], s2[2];
#pragma unroll
    for (int r = 0; r < 2; ++r) {          // batch ALL loads first
      int vid = vid0 + r;
      int b = vid / 784;
      int ll = vid - b * 784;
      const float* src = x + ((size_t)b * LL + 1 + ll) * DIMC;
      s[r] = 0.f; s2[r] = 0.f;
#pragma unroll
      for (int c = 0; c < 6; ++c) {
        float4 vv = *reinterpret_cast<const float4*>(src + sub * 4 + c * 64);
        v[r][c] = vv;
        s[r]  += vv.x + vv.y + vv.z + vv.w;
        s2[r] += vv.x * vv.x + vv.y * vv.y + vv.z * vv.z + vv.w * vv.w;
      }
    }
#pragma unroll
    for (int r = 0; r < 2; ++r) {          // then the store stream
      unsigned short* dst = xbf + (size_t)(vid0 + r) * DIMC;
#pragma unroll
      for (int c = 0; c < 6; ++c) {
        float4 vv = v[r][c];
        union { ushort4v u4; __hip_bfloat162 h[2]; } u;
        u.h[0] = __float22bfloat162_rn(make_float2(vv.x, vv.y));
        u.h[1] = __float22bfloat162_rn(make_float2(vv.z, vv.w));
        *reinterpret_cast<ushort4v*>(dst + sub * 4 + c * 64) = u.u4;
      }
    }
#pragma unroll
    for (int o = 1; o < 16; o <<= 1) {     // 16-lane group reduce, ILP-4
#pragma unroll
      for (int r = 0; r < 2; ++r) {
        s[r]  += __shfl_xor(s[r], o);
        s2[r] += __shfl_xor(s2[r], o);
      }
    }
    if (sub == 0) {
      float4 pp = make_float4(s[0], s2[0], s[1], s2[1]);
      *reinterpret_cast<float4*>(&pst[vid0]) = pp;   // vid0 even: 16B aligned
    }
  } else if (blk < PB_CAST) {              // ---- cls ----
    __shared__ float xs[DIMC];
    int idx = blk;                         // < 192
    int b = idx / 3;
    int ch = idx - b * 3;
    for (int c = t; c < DIMC; c += 256) xs[c] = x[(size_t)b * LL * DIMC + c];
    __syncthreads();
    int o = ch * 256 + t;
    const float* wr = wconv + (size_t)o * DIMC;
    float a0 = 0.f, a1 = 0.f;
#pragma unroll 4
    for (int c = 0; c < DIMC; c += 8) {
      float4 w0 = *reinterpret_cast<const float4*>(wr + c);
      float4 w1 = *reinterpret_cast<const float4*>(wr + c + 4);
      float4 p0 = *reinterpret_cast<const float4*>(&xs[c]);
      float4 p1 = *reinterpret_cast<const float4*>(&xs[c + 4]);
      a0 += w0.x * p0.x + w0.y * p0.y + w0.z * p0.z + w0.w * p0.w;
      a1 += w1.x * p1.x + w1.y * p1.y + w1.z * p1.z + w1.w * p1.w;
    }
    out[(size_t)b * 197 * ODIM + o] = a0 + a1;
  } else if (blk < PB_WBF) {               // ---- bias2 = (gsum, bias) ----
    int o = (blk - PB_BIAS) * 4 + wv;      // < 768
    const float* wr = wred + (size_t)o * FDIM;
    float sb = 0.f, sg = 0.f;
#pragma unroll
    for (int c = 0; c < 6; ++c) {
      int f = lane * 4 + c * 256;
      float4 w = *reinterpret_cast<const float4*>(wr + f);
      float4 be = *reinterpret_cast<const float4*>(beta + f);
      float4 ga = *reinterpret_cast<const float4*>(gamma + f);
      sb += w.x * be.x + w.y * be.y + w.z * be.z + w.w * be.w;
      sg += w.x * ga.x + w.y * ga.y + w.z * ga.z + w.w * ga.w;
    }
#pragma unroll
    for (int o2 = 32; o2 > 0; o2 >>= 1) {
      sb += __shfl_down(sb, o2);
      sg += __shfl_down(sg, o2);
    }
    if (lane == 0) bias2[o] = make_float2(sg, sb);
  } else {                                 // ---- wbf = bf16(gamma*w_red) ----
    int idx4 = (blk - PB_WBF) * 256 + t;   // < 294912
    int e0 = idx4 * 4;
    int f = e0 % FDIM;
    float4 w = *reinterpret_cast<const float4*>(wred + e0);
    float4 g = *reinterpret_cast<const float4*>(gamma + f);
    ushort4v u;
    u.x = f2bf(w.x * g.x); u.y = f2bf(w.y * g.y);
    u.z = f2bf(w.z * g.z); u.w = f2bf(w.w * g.w);
    *reinterpret_cast<ushort4v*>(wbf + e0) = u;
  }
}

// ---------------------------------------------------------------------------
// GEMM on xbf: tile 128x128, BK=32, DOUBLE-buffered at R4's LDS budget
// (33 KB: each buffer packs 128 rows x 32 k as [rho=r&63][(r>>6)*4+kc] 16B
// chunks, XOR-swizzled over 8 chunks -> same conflict-free ds_read_b128 as
// R4). One barrier per K-step (48 total, same as R4's 2x24); next tile's
// loads are issued BEFORE the compute phase and drained AFTER it, so each
// step's load latency gets ~150-300 cycles of MFMA cover instead of 0.
// Affine-LN epilogue: C = rs[m]*acc + nmu[m]*gsum[o] + bias[o].
// ---------------------------------------------------------------------------
__global__ __launch_bounds__(256) void gemm_kernel(
    const unsigned short* __restrict__ xbf,
    const unsigned short* __restrict__ wbf,
    const float2* __restrict__ pst, const float2* __restrict__ bias2,
    float* __restrict__ out) {
  __shared__ unsigned short As[2][64 * 64];   // 2 x 8 KB (128r x 32k packed)
  __shared__ unsigned short Bs[2][64 * 64];   // 2 x 8 KB
  __shared__ float2 st[128];                  // per-row (rs, nmu)

  const int t = threadIdx.x;

  // ---- chunked bijective XCD swizzle: NWG=588, q=73, r=4 ----
  const int NWG = (ODIM / 128) * (MROWS / 128);   // 588
  const int qq = NWG >> 3, rr = NWG & 7;
  int bid = blockIdx.x;
  int xcd = bid & 7, pos = bid >> 3;
  int wg = (xcd < rr) ? xcd * (qq + 1) + pos
                      : rr * (qq + 1) + (xcd - rr) * qq + pos;
  int my = wg / 6;                        // consecutive wg share my (A-panel)
  int nx = wg - my * 6;
  const int mBase = my * 128;
  const int nBase = nx * 128;

  // Prologue stats combine: thread r<128 -> row mBase+r's (rs, nmu).
  if (t < 128) {
    int m = mBase + t;
    int b = m / NPATCH;
    int n = m - b * NPATCH;
    int i = n / 14;
    int j = n - i * 14;
    int base = b * 784 + i * 56 + j * 2;
    float2 p0 = pst[base];
    float2 p1 = pst[base + 28];
    float2 p2 = pst[base + 1];
    float2 p3 = pst[base + 29];
    float s = p0.x + p1.x + p2.x + p3.x;
    float s2 = p0.y + p1.y + p2.y + p3.y;
    float mu = s * (1.f / FDIM);
    float var = s2 * (1.f / FDIM) - mu * mu;
    float rs = rsqrtf(var + 1e-5f);
    st[t] = make_float2(rs, -mu * rs);
  }

  // Staging precompute: 512 slots per operand, 2/thread. Slot s -> LDS pos
  // (rho = s>>3, chunkpos = s&7); it holds logical (row r, k-chunk kc) with
  // g = chunkpos ^ (rho&7), r = rho + 64*(g>>2), kc = g&3.
  const unsigned short* agp[2];
  const unsigned short* bgp[2];
  unsigned int ldso[2];
#pragma unroll
  for (int p = 0; p < 2; ++p) {
    int s = p * 256 + t;
    int rho = s >> 3;
    int g = (s & 7) ^ (rho & 7);
    int r = rho + ((g >> 2) << 6);
    int kc = g & 3;
    int m = mBase + r;
    int b = m / NPATCH;
    int n = m - b * NPATCH;
    int i = n / 14;
    int j = n - i * 14;
    agp[p] = xbf + ((size_t)b * 784 + i * 56 + j * 2) * DIMC + kc * 8;
    bgp[p] = wbf + (size_t)(nBase + r) * FDIM + kc * 8;
    ldso[p] = (unsigned)s * 8;
  }

  const int wv = t >> 6;
  const int lane = t & 63;
  const int ln15 = lane & 15;
  const int quad = lane >> 4;
  const int wm = wv >> 1;
  const int wn = wv & 1;

  // Fragment LDS offsets (ushort units): row rA -> rho=rA&63, hi=rA>>6,
  // chunk = (hi*4 + quad) ^ (rho&7).
  unsigned int aoff[4], boff[4];
#pragma unroll
  for (int mt = 0; mt < 4; ++mt) {
    int rho = mt * 16 + ln15;             // wm*64+... & 63
    aoff[mt] = (unsigned)(rho * 64 + (((wm * 4 + quad) ^ (rho & 7)) * 8));
    boff[mt] = (unsigned)(rho * 64 + (((wn * 4 + quad) ^ (rho & 7)) * 8));
  }

  floatx4 acc[4][4];
#pragma unroll
  for (int mt = 0; mt < 4; ++mt)
#pragma unroll
    for (int nt = 0; nt < 4; ++nt)
      acc[mt][nt] = floatx4{0.f, 0.f, 0.f, 0.f};

  // Prologue: stage tile 0 (q=0, kk=0) into buffer 0.
#pragma unroll
  for (int p = 0; p < 2; ++p) {
    gload_lds16(agp[p], &As[0][ldso[p]]);
    gload_lds16(bgp[p], &Bs[0][ldso[p]]);
  }
  __syncthreads();                         // vmcnt(0) drain + barrier

  int nq = 0, nkk = 0;                     // indices of NEXT tile
  for (int kt = 0; kt < FDIM / 32; ++kt) {
    const int cur = kt & 1;
    if (kt + 1 < FDIM / 32) {              // issue next-tile loads FIRST
      if (++nkk == 12) { nkk = 0; ++nq; }
      int ao = ((nq & 1) * 28 + ((nq >> 1) & 1)) * DIMC + nkk * 32;
#pragma unroll
      for (int p = 0; p < 2; ++p) {
        gload_lds16(agp[p] + ao, &As[cur ^ 1][ldso[p]]);
        bgp[p] += 32;
        gload_lds16(bgp[p], &Bs[cur ^ 1][ldso[p]]);
      }
    }
    // ---- compute tile kt (covers the in-flight loads) ----
    bf16x8 af[4], bfr[4];
#pragma unroll
    for (int mt = 0; mt < 4; ++mt)
      af[mt] = *reinterpret_cast<const bf16x8*>(&As[cur][aoff[mt]]);
#pragma unroll
    for (int nt = 0; nt < 4; ++nt)
      bfr[nt] = *reinterpret_cast<const bf16x8*>(&Bs[cur][boff[nt]]);
#pragma unroll
    for (int mt = 0; mt < 4; ++mt)
#pragma unroll
      for (int nt = 0; nt < 4; ++nt)
        acc[mt][nt] = __builtin_amdgcn_mfma_f32_16x16x32_bf16(
            af[mt], bfr[nt], acc[mt][nt], 0, 0, 0);
    __syncthreads();   // drains this step's stage (vmcnt0) + readers done
  }

  // Epilogue. C/D: col = ln15, row = quad*4 + reg  [m89/m91].
  // C = rs*acc + nmu*gsum + bias.
  float2 gb[4];
#pragma unroll
  for (int nt = 0; nt < 4; ++nt)
    gb[nt] = bias2[nBase + wn * 64 + nt * 16 + ln15];
#pragma unroll
  for (int mt = 0; mt < 4; ++mt) {
#pragma unroll
    for (int r = 0; r < 4; ++r) {
      int rloc = wm * 64 + mt * 16 + quad * 4 + r;
      float2 sn = st[rloc];              // (rs, nmu)
      int m = mBase + rloc;
      int b = m / NPATCH;
      int n = m - b * NPATCH;
      float* orow = out + ((size_t)b * 197 + 1 + n) * ODIM + nBase + wn * 64;
#pragma unroll
      for (int nt = 0; nt < 4; ++nt) {
        float val = fmaf(acc[mt][nt][r], sn.x,
                         fmaf(sn.y, gb[nt].x, gb[nt].y));
        __builtin_nontemporal_store(val, &orow[nt * 16 + ln15]);
      }
    }
  }
}

extern "C" void kernel_launch(void* const* d_in, const int* in_sizes, int n_in,
                              void* d_out, int out_size, void* d_ws, size_t ws_size,
                              hipStream_t stream) {
  const float* x     = (const float*)d_in[0];   // (64, 785, 384)
  const float* wred  = (const float*)d_in[1];   // (768, 1536)
  const float* wconv = (const float*)d_in[2];   // (768, 384)
  const float* gamma = (const float*)d_in[3];   // (1536,)
  const float* beta  = (const float*)d_in[4];   // (1536,)
  float* out = (float*)d_out;                   // (64, 197, 768)

  unsigned short* xbf = (unsigned short*)d_ws;
  unsigned short* wbf = (unsigned short*)((char*)d_ws + WS_WBF_OFF);
  float2* pst         = (float2*)((char*)d_ws + WS_PST_OFF);
  float2* bias2       = (float2*)((char*)d_ws + WS_B2_OFF);

  prep_kernel<<<dim3(PREP_BLOCKS), 256, 0, stream>>>(x, wred, wconv, gamma,
                                                     beta, xbf, wbf, pst,
                                                     bias2, out);
  gemm_kernel<<<dim3((ODIM / 128) * (MROWS / 128)), 256, 0, stream>>>(
      xbf, wbf, pst, bias2, out);
}